// Round 6
// baseline (724.263 us; speedup 1.0000x reference)
//
#include <hip/hip_runtime.h>
#include <hip/hip_bf16.h>
#include <cstdint>
#include <cstddef>

// ---------------------------------------------------------------------------
// STGNN forward. Round 6:
//  - CSR adjacency (count/scan/place, 4B entries) replaces CAP-strided
//    buckets: kills the 49MB write-amplified scatter (R5 top dispatch).
//  - Edge weights computed inline in gather from aS/aD (deletes edge_w
//    passes + w_e stream; softmax shift dropped per R5 analysis).
//  - GEMM widened to 64x256 tiles: wave w = head w, 4x4 MFMA frags,
//    8 ds_read_b128/wave/k-iter vs 17, A staged once, 4x fewer barriers.
// ---------------------------------------------------------------------------

#define LRELU_SLOPE 0.2f

typedef __attribute__((ext_vector_type(8))) short short8;
typedef __attribute__((ext_vector_type(4))) float floatx4;

__device__ __forceinline__ float bf2f(ushort u) {
    union { unsigned int u32; float f; } v; v.u32 = ((unsigned int)u) << 16; return v.f;
}
__device__ __forceinline__ ushort f2bf(float x) {
    union { float f; unsigned int u; } v; v.f = x;
    unsigned int r = (v.u + 0x7FFFu + ((v.u >> 16) & 1u)) >> 16;
    return (ushort)r;
}

// ---------------- elementwise fp32 -> bf16 cast (4/thread) ------------------
__global__ __launch_bounds__(256) void cast_bf16(
    const float* __restrict__ x, ushort* __restrict__ y, int n4)
{
    const int idx = blockIdx.x * blockDim.x + threadIdx.x;
    if (idx >= n4) return;
    float4 v = ((const float4*)x)[idx];
    ushort4 o;
    o.x = f2bf(v.x); o.y = f2bf(v.y); o.z = f2bf(v.z); o.w = f2bf(v.w);
    ((ushort4*)y)[idx] = o;
}

// ------------- weight transpose+cast: W[K][256] f32 -> WT[256][K] bf16 ------
__global__ __launch_bounds__(256) void wtrans(
    const float* __restrict__ W, ushort* __restrict__ WT, int K)
{
    const int idx = blockIdx.x * blockDim.x + threadIdx.x;
    if (idx >= K * 256) return;
    const int k = idx >> 8, n = idx & 255;
    WT[n * K + k] = f2bf(W[idx]);
}

// ---- 4x fused 256x256 weight transpose (one dispatch) ----------------------
__global__ __launch_bounds__(256) void wtrans4(
    const float* __restrict__ W0, const float* __restrict__ W1,
    const float* __restrict__ W2, const float* __restrict__ W3,
    ushort* __restrict__ T)   // 4 contiguous 256x256 bf16 blocks
{
    const int idx = blockIdx.x * blockDim.x + threadIdx.x; // 4*65536
    if (idx >= 4 * 65536) return;
    const int m = idx >> 16, r = idx & 65535;
    const int k = r >> 8, n = r & 255;
    const float* W = (m == 0) ? W0 : (m == 1) ? W1 : (m == 2) ? W2 : W3;
    T[(size_t)m * 65536 + n * 256 + k] = f2bf(W[r]);
}

// ---------------- bf16 MFMA GEMM: C[M,256] = act(A[M,K] @ B + bias) ---------
// 64x256 tile per block: wave w handles cols 64w..64w+63 (= head w), all 64
// rows (4 row-frags x 4 col-frags). Optional fused attention dots per head.
__global__ __launch_bounds__(256) void gemm_bf16(
    const ushort* __restrict__ A, const ushort* __restrict__ Bt,
    const float* __restrict__ bias, float* __restrict__ Cf,
    ushort* __restrict__ Cb, int M, int K, int do_relu,
    const float* __restrict__ attS, const float* __restrict__ attD,
    float* __restrict__ aSo, float* __restrict__ aDo)
{
    __shared__ short As[64][40];    // +8 pad
    __shared__ short Bs[256][40];
    const int tid  = threadIdx.x;
    const int row0 = blockIdx.x * 64;
    const int ar = tid >> 2;          // A stage row
    const int ak = (tid & 3) * 8;     // A stage k-chunk
    const int w    = tid >> 6;        // wave = head = col group
    const int lane = tid & 63;
    const int cix  = lane & 15;
    const int ksel = (lane >> 4) * 8;

    floatx4 acc[4][4];
#pragma unroll
    for (int r = 0; r < 4; ++r)
#pragma unroll
        for (int c = 0; c < 4; ++c) acc[r][c] = (floatx4){0.f, 0.f, 0.f, 0.f};

    for (int k0 = 0; k0 < K; k0 += 32) {
        short8 av = {0,0,0,0,0,0,0,0};
        if (row0 + ar < M)
            av = *(const short8*)(A + (size_t)(row0 + ar) * K + k0 + ak);
        *(short8*)&As[ar][ak] = av;
        const ushort* bp = Bt + (size_t)tid * K + k0;
        *(short8*)&Bs[tid][0]  = *(const short8*)(bp + 0);
        *(short8*)&Bs[tid][8]  = *(const short8*)(bp + 8);
        *(short8*)&Bs[tid][16] = *(const short8*)(bp + 16);
        *(short8*)&Bs[tid][24] = *(const short8*)(bp + 24);
        __syncthreads();
        short8 af[4], bf[4];
#pragma unroll
        for (int r = 0; r < 4; ++r) af[r] = *(const short8*)&As[16 * r + cix][ksel];
#pragma unroll
        for (int c = 0; c < 4; ++c) bf[c] = *(const short8*)&Bs[64 * w + 16 * c + cix][ksel];
#pragma unroll
        for (int r = 0; r < 4; ++r)
#pragma unroll
            for (int c = 0; c < 4; ++c)
                acc[r][c] = __builtin_amdgcn_mfma_f32_16x16x32_bf16(af[r], bf[c], acc[r][c], 0, 0, 0);
        __syncthreads();
    }

    // C/D layout: col = cix (within 16-tile), row = (lane>>4)*4 + i
#pragma unroll
    for (int r = 0; r < 4; ++r) {
        const int rbase = row0 + 16 * r + (lane >> 4) * 4;
#pragma unroll
        for (int c = 0; c < 4; ++c) {
            const int col = 64 * w + 16 * c + cix;
            const float bv = bias ? bias[col] : 0.f;
#pragma unroll
            for (int i = 0; i < 4; ++i) {
                const int row = rbase + i;
                if (row < M) {
                    float v = acc[r][c][i] + bv;
                    if (do_relu) v = fmaxf(v, 0.f);
                    const size_t off = (size_t)row * 256 + col;
                    if (Cf) Cf[off] = v;
                    if (Cb) Cb[off] = f2bf(v);
                }
            }
        }
    }

    // fused per-row attention dots (raw fp32 acc, pre-bias/relu); head = w
    if (attS) {
        float sA[4][4], sD[4][4];
#pragma unroll
        for (int r = 0; r < 4; ++r)
#pragma unroll
            for (int i = 0; i < 4; ++i) { sA[r][i] = 0.f; sD[r][i] = 0.f; }
#pragma unroll
        for (int c = 0; c < 4; ++c) {
            const int col = 64 * w + 16 * c + cix;
            const float as_v = attS[col];
            const float ad_v = attD ? attD[col] : 0.f;
#pragma unroll
            for (int r = 0; r < 4; ++r)
#pragma unroll
                for (int i = 0; i < 4; ++i) {
                    sA[r][i] += acc[r][c][i] * as_v;
                    sD[r][i] += acc[r][c][i] * ad_v;
                }
        }
#pragma unroll
        for (int off = 1; off < 16; off <<= 1)
#pragma unroll
            for (int r = 0; r < 4; ++r)
#pragma unroll
                for (int i = 0; i < 4; ++i) {
                    sA[r][i] += __shfl_xor(sA[r][i], off);
                    sD[r][i] += __shfl_xor(sD[r][i], off);
                }
        if (cix == 0) {
#pragma unroll
            for (int r = 0; r < 4; ++r)
#pragma unroll
                for (int i = 0; i < 4; ++i) {
                    const int row = row0 + 16 * r + (lane >> 4) * 4 + i;
                    if (row < M) {
                        aSo[(size_t)row * 4 + w] = sA[r][i];
                        if (aDo) aDo[(size_t)row * 4 + w] = sD[r][i];
                    }
                }
        }
    }
}

// ------ fold ct-dst attention through the projection: wfold[k,h] ------------
__global__ void fold_ct(const float* __restrict__ W, const float* __restrict__ ad,
                        float* __restrict__ wfold)
{
    int idx = blockIdx.x * blockDim.x + threadIdx.x; // 1024 = 256*4
    if (idx >= 1024) return;
    int k = idx >> 2, h = idx & 3;
    float s = 0.f;
#pragma unroll 8
    for (int c = 0; c < 64; ++c) s += W[(size_t)k * 256 + h * 64 + c] * ad[h * 64 + c];
    wfold[idx] = s;
}

// aD[n,h] = ht[n,:] @ wfold[:,h]   (ht in bf16)
__global__ __launch_bounds__(256) void alpha_from_fold(
    const ushort* __restrict__ ht, const float* __restrict__ wfold,
    float* __restrict__ aD, int N)
{
    __shared__ float wf[1024];
    const int tid = threadIdx.x;
    *(float4*)&wf[tid * 4] = *(const float4*)&wfold[tid * 4];
    __syncthreads();
    const int idx = blockIdx.x * 256 + tid;
    if (idx >= N * 4) return;
    const int n = idx >> 2, h = idx & 3;
    const ushort* row = ht + (size_t)n * 256;
    float s = 0.f;
#pragma unroll
    for (int k = 0; k < 256; k += 4) {
        ushort4 r4 = *(const ushort4*)(row + k);
        s += bf2f(r4.x) * wf[(k + 0) * 4 + h] + bf2f(r4.y) * wf[(k + 1) * 4 + h]
           + bf2f(r4.z) * wf[(k + 2) * 4 + h] + bf2f(r4.w) * wf[(k + 3) * 4 + h];
    }
    aD[idx] = s;
}

// ---- CSR build: count -> scan -> place -------------------------------------
__global__ __launch_bounds__(256) void csr_count_tt(
    const int* __restrict__ src, const int* __restrict__ dst, int E,
    int* __restrict__ cntA, int* __restrict__ cntB)
{
    const int e = blockIdx.x * blockDim.x + threadIdx.x;
    if (e >= E) return;
    atomicAdd(&cntA[dst[e]], 1);
    atomicAdd(&cntB[src[e]], 1);
}

__global__ __launch_bounds__(256) void csr_count(
    const int* __restrict__ dst, int E, int* __restrict__ cnt)
{
    const int e = blockIdx.x * blockDim.x + threadIdx.x;
    if (e >= E) return;
    atomicAdd(&cnt[dst[e]], 1);
}

// exclusive scan of 3 arrays (blockIdx.x selects), single 1024-thread block
__global__ __launch_bounds__(1024) void scan_excl(
    const int* __restrict__ cnt, int* __restrict__ ptr, int* __restrict__ cur, int N)
{
    __shared__ int part[1024];
    const int a = blockIdx.x;
    const int* c = cnt + (size_t)a * N;
    int* p = ptr + (size_t)a * (N + 1);
    int* q = cur + (size_t)a * N;
    const int tid = threadIdx.x;
    const int chunk = (N + 1023) / 1024;
    const int base = tid * chunk;
    int s = 0;
    for (int j = 0; j < chunk; ++j) {
        const int idx = base + j;
        if (idx < N) s += c[idx];
    }
    part[tid] = s;
    __syncthreads();
    for (int off = 1; off < 1024; off <<= 1) {
        int v = (tid >= off) ? part[tid - off] : 0;
        __syncthreads();
        part[tid] += v;
        __syncthreads();
    }
    int run = part[tid] - s;   // exclusive base
    for (int j = 0; j < chunk; ++j) {
        const int idx = base + j;
        if (idx < N) {
            p[idx] = run; q[idx] = run;
            run += c[idx];
        }
    }
    if (tid == 1023) p[N] = part[1023];
}

__global__ __launch_bounds__(256) void csr_place_tt(
    const int* __restrict__ src, const int* __restrict__ dst, int E,
    int* __restrict__ curA, int* __restrict__ eA,
    int* __restrict__ curB, int* __restrict__ eB)
{
    const int e = blockIdx.x * blockDim.x + threadIdx.x;
    if (e >= E) return;
    const int s = src[e], d = dst[e];
    eA[atomicAdd(&curA[d], 1)] = s;
    eB[atomicAdd(&curB[s], 1)] = d;
}

__global__ __launch_bounds__(256) void csr_place(
    const int* __restrict__ src, const int* __restrict__ dst, int E,
    int* __restrict__ cur, int* __restrict__ ecsr)
{
    const int e = blockIdx.x * blockDim.x + threadIdx.x;
    if (e >= E) return;
    ecsr[atomicAdd(&cur[dst[e]], 1)] = src[e];
}

// ---- gather: one WAVE per node, weights inline from aS/aD ------------------
__global__ __launch_bounds__(256) void gat_gather_csr(
    const int* __restrict__ ptr, const int* __restrict__ ecsr,
    const float* __restrict__ aS, const float* __restrict__ aD,
    const ushort* __restrict__ xs, const float* __restrict__ bias,
    float scale, float* __restrict__ acc, int N, int has_self, int init)
{
    const int n = blockIdx.x * 4 + (threadIdx.x >> 6);
    if (n >= N) return;
    const int lane = threadIdx.x & 63;
    const int h  = lane >> 4;          // 16 lanes per head
    const int c4 = lane << 2;          // channel base, 0..252
    const float aDn = aD[(size_t)n * 4 + h];

    float4 facc = {0.f, 0.f, 0.f, 0.f};
    float dacc = 0.f;
    if (has_self) {
        float a = aS[(size_t)n * 4 + h] + aDn;
        a = (a >= 0.f) ? a : LRELU_SLOPE * a;
        const float w = __expf(a);
        const ushort4 x = *(const ushort4*)(xs + (size_t)n * 256 + c4);
        facc.x = w * bf2f(x.x); facc.y = w * bf2f(x.y);
        facc.z = w * bf2f(x.z); facc.w = w * bf2f(x.w);
        dacc = w;
    }

    const int beg = ptr[n], end = ptr[n + 1];
    int i = beg;
    for (; i + 4 <= end; i += 4) {
        const int s0 = ecsr[i], s1 = ecsr[i + 1], s2 = ecsr[i + 2], s3 = ecsr[i + 3];
        float a0 = aS[(size_t)s0 * 4 + h] + aDn;
        float a1 = aS[(size_t)s1 * 4 + h] + aDn;
        float a2 = aS[(size_t)s2 * 4 + h] + aDn;
        float a3 = aS[(size_t)s3 * 4 + h] + aDn;
        const ushort4 x0 = *(const ushort4*)(xs + (size_t)s0 * 256 + c4);
        const ushort4 x1 = *(const ushort4*)(xs + (size_t)s1 * 256 + c4);
        const ushort4 x2 = *(const ushort4*)(xs + (size_t)s2 * 256 + c4);
        const ushort4 x3 = *(const ushort4*)(xs + (size_t)s3 * 256 + c4);
        a0 = (a0 >= 0.f) ? a0 : LRELU_SLOPE * a0;
        a1 = (a1 >= 0.f) ? a1 : LRELU_SLOPE * a1;
        a2 = (a2 >= 0.f) ? a2 : LRELU_SLOPE * a2;
        a3 = (a3 >= 0.f) ? a3 : LRELU_SLOPE * a3;
        const float w0 = __expf(a0), w1 = __expf(a1);
        const float w2 = __expf(a2), w3 = __expf(a3);
        facc.x += w0 * bf2f(x0.x) + w1 * bf2f(x1.x) + w2 * bf2f(x2.x) + w3 * bf2f(x3.x);
        facc.y += w0 * bf2f(x0.y) + w1 * bf2f(x1.y) + w2 * bf2f(x2.y) + w3 * bf2f(x3.y);
        facc.z += w0 * bf2f(x0.z) + w1 * bf2f(x1.z) + w2 * bf2f(x2.z) + w3 * bf2f(x3.z);
        facc.w += w0 * bf2f(x0.w) + w1 * bf2f(x1.w) + w2 * bf2f(x2.w) + w3 * bf2f(x3.w);
        dacc   += w0 + w1 + w2 + w3;
    }
    for (; i < end; ++i) {
        const int s = ecsr[i];
        float a = aS[(size_t)s * 4 + h] + aDn;
        a = (a >= 0.f) ? a : LRELU_SLOPE * a;
        const float w = __expf(a);
        const ushort4 x = *(const ushort4*)(xs + (size_t)s * 256 + c4);
        facc.x += w * bf2f(x.x); facc.y += w * bf2f(x.y);
        facc.z += w * bf2f(x.z); facc.w += w * bf2f(x.w);
        dacc   += w;
    }

    const float inv = 1.f / fmaxf(dacc, 1e-16f);
    const float4 bv = *(const float4*)(bias + c4);
    float4 v;
    v.x = scale * (facc.x * inv + bv.x);
    v.y = scale * (facc.y * inv + bv.y);
    v.z = scale * (facc.z * inv + bv.z);
    v.w = scale * (facc.w * inv + bv.w);
    float4* ap = (float4*)(acc + (size_t)n * 256 + c4);
    if (init) {
        *ap = v;
    } else {
        float4 o = *ap;
        o.x += v.x; o.y += v.y; o.z += v.z; o.w += v.w;
        *ap = o;
    }
}

// ---- skip + relu + cast: htb = bf16(relu(acc + htb)) in place --------------
__global__ __launch_bounds__(256) void combine_relu(
    const float* __restrict__ acc, ushort* __restrict__ htb, int total4)
{
    const int idx = blockIdx.x * blockDim.x + threadIdx.x;
    if (idx >= total4) return;
    float4 a = ((const float4*)acc)[idx];
    ushort4 hb = ((const ushort4*)htb)[idx];
    ushort4 o;
    o.x = f2bf(fmaxf(a.x + bf2f(hb.x), 0.f));
    o.y = f2bf(fmaxf(a.y + bf2f(hb.y), 0.f));
    o.z = f2bf(fmaxf(a.z + bf2f(hb.z), 0.f));
    o.w = f2bf(fmaxf(a.w + bf2f(hb.w), 0.f));
    ((ushort4*)htb)[idx] = o;
}

// ---------------------------------------------------------------------------
extern "C" void kernel_launch(void* const* d_in, const int* in_sizes, int n_in,
                              void* d_out, int out_size, void* d_ws, size_t ws_size,
                              hipStream_t stream)
{
    const int NT   = in_sizes[0] / 128;
    const int NC   = in_sizes[1] / 64;
    const int E_TT = in_sizes[2] / 2;
    const int E_CT = in_sizes[3];

    const float* x_target = (const float*)d_in[0];
    const float* x_context= (const float*)d_in[1];
    const int*   ei_tt    = (const int*)d_in[2];
    const int*   ei_ct_src= (const int*)d_in[3];
    const int*   ei_ct_dst= (const int*)d_in[4];
    const float* Wt   = (const float*)d_in[5];
    const float* bt   = (const float*)d_in[6];
    const float* Wc   = (const float*)d_in[7];
    const float* bc   = (const float*)d_in[8];
    const float* W_s2d  = (const float*)d_in[9];
    const float* as_s2d = (const float*)d_in[10];
    const float* ad_s2d = (const float*)d_in[11];
    const float* b_s2d  = (const float*)d_in[12];
    const float* W_d2s  = (const float*)d_in[13];
    const float* as_d2s = (const float*)d_in[14];
    const float* ad_d2s = (const float*)d_in[15];
    const float* b_d2s  = (const float*)d_in[16];
    const float* W_ct_src = (const float*)d_in[17];
    const float* W_ct_dst = (const float*)d_in[18];
    const float* as_ct  = (const float*)d_in[19];
    const float* ad_ct  = (const float*)d_in[20];
    const float* b_ct   = (const float*)d_in[21];
    const float* W_out  = (const float*)d_in[22];
    const float* b_out  = (const float*)d_in[23];
    float* out = (float*)d_out;

    const int* tt_src = ei_tt;
    const int* tt_dst = ei_tt + E_TT;

    // ---- workspace carve-up ----
    float* ws = (float*)d_ws;
    size_t o = 0;
    float* acc = ws + o;               o += (size_t)NT * 256;
    ushort* htb = (ushort*)(ws + o);   o += (size_t)NT * 128;   // NT*256 bf16
    ushort* Pb  = (ushort*)(ws + o);   o += (size_t)NT * 128;
    ushort* hcb = (ushort*)(ws + o);   o += (size_t)NC * 128;
    ushort* PSb = (ushort*)(ws + o);   o += (size_t)NC * 128;
    ushort* xtb = (ushort*)(ws + o);   o += (size_t)NT * 64;    // NT*128 bf16
    ushort* xcb = (ushort*)(ws + o);   o += (size_t)NC * 32;
    int* eA = (int*)(ws + o);          o += (size_t)E_TT;
    int* eB = (int*)(ws + o);          o += (size_t)E_TT;
    int* eC = (int*)(ws + o);          o += (size_t)E_CT;
    int* cnt = (int*)(ws + o);         o += (size_t)NT * 3;     // A,B,C
    int* ptr = (int*)(ws + o);         o += (size_t)(NT + 1) * 3;
    int* cur = (int*)(ws + o);         o += (size_t)NT * 3;
    float* aS  = ws + o;               o += (size_t)NT * 4;
    float* aD  = ws + o;               o += (size_t)NT * 4;
    float* wfold = ws + o;             o += 1024;
    ushort* WtT   = (ushort*)(ws + o); o += 128 * 256 / 2;
    ushort* WcT   = (ushort*)(ws + o); o += 64 * 256 / 2;
    ushort* W4T   = (ushort*)(ws + o); o += 4 * 256 * 256 / 2;  // s2d,d2s,ct_src,out
    (void)ws_size; (void)n_in; (void)out_size;

    ushort* Ws2dT = W4T;
    ushort* Wd2sT = W4T + 65536;
    ushort* WctsT = W4T + 2 * 65536;
    ushort* WoutT = W4T + 3 * 65536;

    int* cntA = cnt;           int* cntB = cnt + NT;           int* cntC = cnt + 2 * NT;
    int* ptrA = ptr;           int* ptrB = ptr + (NT + 1);     int* ptrC = ptr + 2 * (NT + 1);
    int* curA = cur;           int* curB = cur + NT;           int* curC = cur + 2 * NT;

    const dim3 blk(256);
    const int gN4 = (NT * 4 + 255) / 256;
    const int gGat = (NT + 3) / 4;

    auto gemm = [&](const ushort* A, const ushort* Bt, const float* bias,
                    float* Cf, ushort* Cb, int M, int K, int relu,
                    const float* attS, const float* attD, float* aSo, float* aDo) {
        dim3 grid((M + 63) / 64);
        hipLaunchKernelGGL(gemm_bf16, grid, blk, 0, stream, A, Bt, bias, Cf, Cb,
                           M, K, relu, attS, attD, aSo, aDo);
    };

    // 0) casts, weight transposes, CSR topology (feature-independent)
    hipMemsetAsync(cnt, 0, (size_t)NT * 3 * sizeof(int), stream);
    hipLaunchKernelGGL(cast_bf16, dim3((NT * 128 / 4 + 255) / 256), blk, 0, stream,
                       x_target, xtb, NT * 128 / 4);
    hipLaunchKernelGGL(cast_bf16, dim3((NC * 64 / 4 + 255) / 256), blk, 0, stream,
                       x_context, xcb, NC * 64 / 4);
    hipLaunchKernelGGL(wtrans, dim3(128), blk, 0, stream, Wt, WtT, 128);
    hipLaunchKernelGGL(wtrans, dim3(64),  blk, 0, stream, Wc, WcT, 64);
    hipLaunchKernelGGL(wtrans4, dim3(1024), blk, 0, stream,
                       W_s2d, W_d2s, W_ct_src, W_out, W4T);
    hipLaunchKernelGGL(csr_count_tt, dim3((E_TT + 255) / 256), blk, 0, stream,
                       tt_src, tt_dst, E_TT, cntA, cntB);
    hipLaunchKernelGGL(csr_count, dim3((E_CT + 255) / 256), blk, 0, stream,
                       ei_ct_dst, E_CT, cntC);
    hipLaunchKernelGGL(scan_excl, dim3(3), dim3(1024), 0, stream, cnt, ptr, cur, NT);
    hipLaunchKernelGGL(csr_place_tt, dim3((E_TT + 255) / 256), blk, 0, stream,
                       tt_src, tt_dst, E_TT, curA, eA, curB, eB);
    hipLaunchKernelGGL(csr_place, dim3((E_CT + 255) / 256), blk, 0, stream,
                       ei_ct_src, ei_ct_dst, E_CT, curC, eC);

    // 1) pretransform
    gemm(xtb, WtT, bt, nullptr, htb, NT, 128, 1, nullptr, nullptr, nullptr, nullptr);
    gemm(xcb, WcT, bc, nullptr, hcb, NC, 64, 1, nullptr, nullptr, nullptr, nullptr);

    // ---- GAT s2d ----
    gemm(htb, Ws2dT, nullptr, nullptr, Pb, NT, 256, 0, as_s2d, ad_s2d, aS, aD);
    hipLaunchKernelGGL(gat_gather_csr, dim3(gGat), blk, 0, stream,
                       ptrA, eA, aS, aD, Pb, b_s2d, 0.25f, acc, NT, 1, 1);

    // ---- GAT d2s (reversed roles) ----
    gemm(htb, Wd2sT, nullptr, nullptr, Pb, NT, 256, 0, as_d2s, ad_d2s, aS, aD);
    hipLaunchKernelGGL(gat_gather_csr, dim3(gGat), blk, 0, stream,
                       ptrB, eB, aS, aD, Pb, b_d2s, 0.25f, acc, NT, 1, 0);

    // ---- GAT ct (no self loops; aD via folded projection) ----
    gemm(hcb, WctsT, nullptr, nullptr, PSb, NC, 256, 0, as_ct, nullptr, aS, nullptr);
    hipLaunchKernelGGL(fold_ct, dim3(4), blk, 0, stream, W_ct_dst, ad_ct, wfold);
    hipLaunchKernelGGL(alpha_from_fold, dim3(gN4), blk, 0, stream, htb, wfold, aD, NT);
    hipLaunchKernelGGL(gat_gather_csr, dim3(gGat), blk, 0, stream,
                       ptrC, eC, aS, aD, PSb, b_ct, 0.5f, acc, NT, 0, 0);

    // ---- skip + relu (bf16 in place), final linear ----
    hipLaunchKernelGGL(combine_relu, dim3((NT * 64 + 255) / 256), blk, 0, stream,
                       acc, htb, NT * 64);
    gemm(htb, WoutT, b_out, out, nullptr, NT, 256, 0, nullptr, nullptr, nullptr, nullptr);
}

// Round 7
// 612.589 us; speedup vs baseline: 1.1823x; 1.1823x over previous
//
#include <hip/hip_runtime.h>
#include <hip/hip_bf16.h>
#include <cstdint>
#include <cstddef>

// ---------------------------------------------------------------------------
// STGNN forward. Round 7: fix the R6 scan regression.
// R6's single-dispatch scan ran 3 blocks (0.4% occupancy) for 128us. Replaced
// with a 3-level hierarchical scan (part-sums / base-scan / final), each level
// fully parallel. Everything else identical to R6.
// ---------------------------------------------------------------------------

#define LRELU_SLOPE 0.2f

typedef __attribute__((ext_vector_type(8))) short short8;
typedef __attribute__((ext_vector_type(4))) float floatx4;

__device__ __forceinline__ float bf2f(ushort u) {
    union { unsigned int u32; float f; } v; v.u32 = ((unsigned int)u) << 16; return v.f;
}
__device__ __forceinline__ ushort f2bf(float x) {
    union { float f; unsigned int u; } v; v.f = x;
    unsigned int r = (v.u + 0x7FFFu + ((v.u >> 16) & 1u)) >> 16;
    return (ushort)r;
}

// ---------------- elementwise fp32 -> bf16 cast (4/thread) ------------------
__global__ __launch_bounds__(256) void cast_bf16(
    const float* __restrict__ x, ushort* __restrict__ y, int n4)
{
    const int idx = blockIdx.x * blockDim.x + threadIdx.x;
    if (idx >= n4) return;
    float4 v = ((const float4*)x)[idx];
    ushort4 o;
    o.x = f2bf(v.x); o.y = f2bf(v.y); o.z = f2bf(v.z); o.w = f2bf(v.w);
    ((ushort4*)y)[idx] = o;
}

// ------------- weight transpose+cast: W[K][256] f32 -> WT[256][K] bf16 ------
__global__ __launch_bounds__(256) void wtrans(
    const float* __restrict__ W, ushort* __restrict__ WT, int K)
{
    const int idx = blockIdx.x * blockDim.x + threadIdx.x;
    if (idx >= K * 256) return;
    const int k = idx >> 8, n = idx & 255;
    WT[n * K + k] = f2bf(W[idx]);
}

// ---- 4x fused 256x256 weight transpose (one dispatch) ----------------------
__global__ __launch_bounds__(256) void wtrans4(
    const float* __restrict__ W0, const float* __restrict__ W1,
    const float* __restrict__ W2, const float* __restrict__ W3,
    ushort* __restrict__ T)   // 4 contiguous 256x256 bf16 blocks
{
    const int idx = blockIdx.x * blockDim.x + threadIdx.x; // 4*65536
    if (idx >= 4 * 65536) return;
    const int m = idx >> 16, r = idx & 65535;
    const int k = r >> 8, n = r & 255;
    const float* W = (m == 0) ? W0 : (m == 1) ? W1 : (m == 2) ? W2 : W3;
    T[(size_t)m * 65536 + n * 256 + k] = f2bf(W[r]);
}

// ---------------- bf16 MFMA GEMM: C[M,256] = act(A[M,K] @ B + bias) ---------
// 64x256 tile per block: wave w handles cols 64w..64w+63 (= head w), all 64
// rows (4 row-frags x 4 col-frags). Optional fused attention dots per head.
__global__ __launch_bounds__(256) void gemm_bf16(
    const ushort* __restrict__ A, const ushort* __restrict__ Bt,
    const float* __restrict__ bias, float* __restrict__ Cf,
    ushort* __restrict__ Cb, int M, int K, int do_relu,
    const float* __restrict__ attS, const float* __restrict__ attD,
    float* __restrict__ aSo, float* __restrict__ aDo)
{
    __shared__ short As[64][40];    // +8 pad
    __shared__ short Bs[256][40];
    const int tid  = threadIdx.x;
    const int row0 = blockIdx.x * 64;
    const int ar = tid >> 2;          // A stage row
    const int ak = (tid & 3) * 8;     // A stage k-chunk
    const int w    = tid >> 6;        // wave = head = col group
    const int lane = tid & 63;
    const int cix  = lane & 15;
    const int ksel = (lane >> 4) * 8;

    floatx4 acc[4][4];
#pragma unroll
    for (int r = 0; r < 4; ++r)
#pragma unroll
        for (int c = 0; c < 4; ++c) acc[r][c] = (floatx4){0.f, 0.f, 0.f, 0.f};

    for (int k0 = 0; k0 < K; k0 += 32) {
        short8 av = {0,0,0,0,0,0,0,0};
        if (row0 + ar < M)
            av = *(const short8*)(A + (size_t)(row0 + ar) * K + k0 + ak);
        *(short8*)&As[ar][ak] = av;
        const ushort* bp = Bt + (size_t)tid * K + k0;
        *(short8*)&Bs[tid][0]  = *(const short8*)(bp + 0);
        *(short8*)&Bs[tid][8]  = *(const short8*)(bp + 8);
        *(short8*)&Bs[tid][16] = *(const short8*)(bp + 16);
        *(short8*)&Bs[tid][24] = *(const short8*)(bp + 24);
        __syncthreads();
        short8 af[4], bf[4];
#pragma unroll
        for (int r = 0; r < 4; ++r) af[r] = *(const short8*)&As[16 * r + cix][ksel];
#pragma unroll
        for (int c = 0; c < 4; ++c) bf[c] = *(const short8*)&Bs[64 * w + 16 * c + cix][ksel];
#pragma unroll
        for (int r = 0; r < 4; ++r)
#pragma unroll
            for (int c = 0; c < 4; ++c)
                acc[r][c] = __builtin_amdgcn_mfma_f32_16x16x32_bf16(af[r], bf[c], acc[r][c], 0, 0, 0);
        __syncthreads();
    }

    // C/D layout: col = cix (within 16-tile), row = (lane>>4)*4 + i
#pragma unroll
    for (int r = 0; r < 4; ++r) {
        const int rbase = row0 + 16 * r + (lane >> 4) * 4;
#pragma unroll
        for (int c = 0; c < 4; ++c) {
            const int col = 64 * w + 16 * c + cix;
            const float bv = bias ? bias[col] : 0.f;
#pragma unroll
            for (int i = 0; i < 4; ++i) {
                const int row = rbase + i;
                if (row < M) {
                    float v = acc[r][c][i] + bv;
                    if (do_relu) v = fmaxf(v, 0.f);
                    const size_t off = (size_t)row * 256 + col;
                    if (Cf) Cf[off] = v;
                    if (Cb) Cb[off] = f2bf(v);
                }
            }
        }
    }

    // fused per-row attention dots (raw fp32 acc, pre-bias/relu); head = w
    if (attS) {
        float sA[4][4], sD[4][4];
#pragma unroll
        for (int r = 0; r < 4; ++r)
#pragma unroll
            for (int i = 0; i < 4; ++i) { sA[r][i] = 0.f; sD[r][i] = 0.f; }
#pragma unroll
        for (int c = 0; c < 4; ++c) {
            const int col = 64 * w + 16 * c + cix;
            const float as_v = attS[col];
            const float ad_v = attD ? attD[col] : 0.f;
#pragma unroll
            for (int r = 0; r < 4; ++r)
#pragma unroll
                for (int i = 0; i < 4; ++i) {
                    sA[r][i] += acc[r][c][i] * as_v;
                    sD[r][i] += acc[r][c][i] * ad_v;
                }
        }
#pragma unroll
        for (int off = 1; off < 16; off <<= 1)
#pragma unroll
            for (int r = 0; r < 4; ++r)
#pragma unroll
                for (int i = 0; i < 4; ++i) {
                    sA[r][i] += __shfl_xor(sA[r][i], off);
                    sD[r][i] += __shfl_xor(sD[r][i], off);
                }
        if (cix == 0) {
#pragma unroll
            for (int r = 0; r < 4; ++r)
#pragma unroll
                for (int i = 0; i < 4; ++i) {
                    const int row = row0 + 16 * r + (lane >> 4) * 4 + i;
                    if (row < M) {
                        aSo[(size_t)row * 4 + w] = sA[r][i];
                        if (aDo) aDo[(size_t)row * 4 + w] = sD[r][i];
                    }
                }
        }
    }
}

// ------ fold ct-dst attention through the projection: wfold[k,h] ------------
__global__ void fold_ct(const float* __restrict__ W, const float* __restrict__ ad,
                        float* __restrict__ wfold)
{
    int idx = blockIdx.x * blockDim.x + threadIdx.x; // 1024 = 256*4
    if (idx >= 1024) return;
    int k = idx >> 2, h = idx & 3;
    float s = 0.f;
#pragma unroll 8
    for (int c = 0; c < 64; ++c) s += W[(size_t)k * 256 + h * 64 + c] * ad[h * 64 + c];
    wfold[idx] = s;
}

// aD[n,h] = ht[n,:] @ wfold[:,h]   (ht in bf16)
__global__ __launch_bounds__(256) void alpha_from_fold(
    const ushort* __restrict__ ht, const float* __restrict__ wfold,
    float* __restrict__ aD, int N)
{
    __shared__ float wf[1024];
    const int tid = threadIdx.x;
    *(float4*)&wf[tid * 4] = *(const float4*)&wfold[tid * 4];
    __syncthreads();
    const int idx = blockIdx.x * 256 + tid;
    if (idx >= N * 4) return;
    const int n = idx >> 2, h = idx & 3;
    const ushort* row = ht + (size_t)n * 256;
    float s = 0.f;
#pragma unroll
    for (int k = 0; k < 256; k += 4) {
        ushort4 r4 = *(const ushort4*)(row + k);
        s += bf2f(r4.x) * wf[(k + 0) * 4 + h] + bf2f(r4.y) * wf[(k + 1) * 4 + h]
           + bf2f(r4.z) * wf[(k + 2) * 4 + h] + bf2f(r4.w) * wf[(k + 3) * 4 + h];
    }
    aD[idx] = s;
}

// ---- CSR build: count -> hierarchical scan -> place ------------------------
__global__ __launch_bounds__(256) void csr_count_tt(
    const int* __restrict__ src, const int* __restrict__ dst, int E,
    int* __restrict__ cntA, int* __restrict__ cntB)
{
    const int e = blockIdx.x * blockDim.x + threadIdx.x;
    if (e >= E) return;
    atomicAdd(&cntA[dst[e]], 1);
    atomicAdd(&cntB[src[e]], 1);
}

__global__ __launch_bounds__(256) void csr_count(
    const int* __restrict__ dst, int E, int* __restrict__ cnt)
{
    const int e = blockIdx.x * blockDim.x + threadIdx.x;
    if (e >= E) return;
    atomicAdd(&cnt[dst[e]], 1);
}

// L1: per-block (1024-elem) sums. grid (nblk, 3).
__global__ __launch_bounds__(256) void scan_part(
    const int* __restrict__ cnt, int* __restrict__ bsum, int N, int nblk)
{
    const int a = blockIdx.y, b = blockIdx.x;
    const int* c = cnt + (size_t)a * N;
    const int i0 = b * 1024 + threadIdx.x * 4;
    int s = 0;
    if (i0 + 3 < N) {
        int4 v = *(const int4*)(c + i0);
        s = v.x + v.y + v.z + v.w;
    } else {
        for (int j = 0; j < 4; ++j) if (i0 + j < N) s += c[i0 + j];
    }
#pragma unroll
    for (int off = 32; off > 0; off >>= 1) s += __shfl_down(s, off);
    __shared__ int wsum[4];
    const int lane = threadIdx.x & 63, w = threadIdx.x >> 6;
    if (lane == 0) wsum[w] = s;
    __syncthreads();
    if (threadIdx.x == 0)
        bsum[a * nblk + b] = wsum[0] + wsum[1] + wsum[2] + wsum[3];
}

// L2: exclusive scan of block sums per array (nblk <= 64): one wave/array.
__global__ __launch_bounds__(256) void scan_base(
    int* __restrict__ bsum, int* __restrict__ ptr, int N, int nblk)
{
    const int a = threadIdx.x >> 6;
    const int lane = threadIdx.x & 63;
    if (a >= 3) return;
    int v = (lane < nblk) ? bsum[a * nblk + lane] : 0;
    int incl = v;
#pragma unroll
    for (int off = 1; off < 64; off <<= 1) {
        int t = __shfl_up(incl, off);
        if (lane >= off) incl += t;
    }
    if (lane < nblk) bsum[a * nblk + lane] = incl - v;     // exclusive base
    if (lane == 63) ptr[(size_t)a * (N + 1) + N] = incl;   // total
}

// L3: final exclusive scan, writes ptr and cur. grid (nblk, 3).
__global__ __launch_bounds__(256) void scan_final(
    const int* __restrict__ cnt, const int* __restrict__ bsum,
    int* __restrict__ ptr, int* __restrict__ cur, int N, int nblk)
{
    const int a = blockIdx.y, b = blockIdx.x;
    const int* c = cnt + (size_t)a * N;
    int* p = ptr + (size_t)a * (N + 1);
    int* q = cur + (size_t)a * N;
    const int i0 = b * 1024 + threadIdx.x * 4;
    int c0 = 0, c1 = 0, c2 = 0, c3 = 0;
    if (i0 + 3 < N) {
        int4 v = *(const int4*)(c + i0);
        c0 = v.x; c1 = v.y; c2 = v.z; c3 = v.w;
    } else {
        if (i0 + 0 < N) c0 = c[i0 + 0];
        if (i0 + 1 < N) c1 = c[i0 + 1];
        if (i0 + 2 < N) c2 = c[i0 + 2];
    }
    const int s = c0 + c1 + c2 + c3;
    const int lane = threadIdx.x & 63, w = threadIdx.x >> 6;
    int incl = s;
#pragma unroll
    for (int off = 1; off < 64; off <<= 1) {
        int t = __shfl_up(incl, off);
        if (lane >= off) incl += t;
    }
    const int laneExcl = incl - s;
    __shared__ int wtot[4];
    if (lane == 63) wtot[w] = incl;
    __syncthreads();
    int wbase = 0;
    for (int j = 0; j < w; ++j) wbase += wtot[j];
    int base = bsum[a * nblk + b] + wbase + laneExcl;
    if (i0 + 0 < N) { p[i0 + 0] = base; q[i0 + 0] = base; } base += c0;
    if (i0 + 1 < N) { p[i0 + 1] = base; q[i0 + 1] = base; } base += c1;
    if (i0 + 2 < N) { p[i0 + 2] = base; q[i0 + 2] = base; } base += c2;
    if (i0 + 3 < N) { p[i0 + 3] = base; q[i0 + 3] = base; }
}

__global__ __launch_bounds__(256) void csr_place_tt(
    const int* __restrict__ src, const int* __restrict__ dst, int E,
    int* __restrict__ curA, int* __restrict__ eA,
    int* __restrict__ curB, int* __restrict__ eB)
{
    const int e = blockIdx.x * blockDim.x + threadIdx.x;
    if (e >= E) return;
    const int s = src[e], d = dst[e];
    eA[atomicAdd(&curA[d], 1)] = s;
    eB[atomicAdd(&curB[s], 1)] = d;
}

__global__ __launch_bounds__(256) void csr_place(
    const int* __restrict__ src, const int* __restrict__ dst, int E,
    int* __restrict__ cur, int* __restrict__ ecsr)
{
    const int e = blockIdx.x * blockDim.x + threadIdx.x;
    if (e >= E) return;
    ecsr[atomicAdd(&cur[dst[e]], 1)] = src[e];
}

// ---- gather: one WAVE per node, weights inline from aS/aD ------------------
__global__ __launch_bounds__(256) void gat_gather_csr(
    const int* __restrict__ ptr, const int* __restrict__ ecsr,
    const float* __restrict__ aS, const float* __restrict__ aD,
    const ushort* __restrict__ xs, const float* __restrict__ bias,
    float scale, float* __restrict__ acc, int N, int has_self, int init)
{
    const int n = blockIdx.x * 4 + (threadIdx.x >> 6);
    if (n >= N) return;
    const int lane = threadIdx.x & 63;
    const int h  = lane >> 4;          // 16 lanes per head
    const int c4 = lane << 2;          // channel base, 0..252
    const float aDn = aD[(size_t)n * 4 + h];

    float4 facc = {0.f, 0.f, 0.f, 0.f};
    float dacc = 0.f;
    if (has_self) {
        float a = aS[(size_t)n * 4 + h] + aDn;
        a = (a >= 0.f) ? a : LRELU_SLOPE * a;
        const float w = __expf(a);
        const ushort4 x = *(const ushort4*)(xs + (size_t)n * 256 + c4);
        facc.x = w * bf2f(x.x); facc.y = w * bf2f(x.y);
        facc.z = w * bf2f(x.z); facc.w = w * bf2f(x.w);
        dacc = w;
    }

    const int beg = ptr[n], end = ptr[n + 1];
    int i = beg;
    for (; i + 4 <= end; i += 4) {
        const int s0 = ecsr[i], s1 = ecsr[i + 1], s2 = ecsr[i + 2], s3 = ecsr[i + 3];
        float a0 = aS[(size_t)s0 * 4 + h] + aDn;
        float a1 = aS[(size_t)s1 * 4 + h] + aDn;
        float a2 = aS[(size_t)s2 * 4 + h] + aDn;
        float a3 = aS[(size_t)s3 * 4 + h] + aDn;
        const ushort4 x0 = *(const ushort4*)(xs + (size_t)s0 * 256 + c4);
        const ushort4 x1 = *(const ushort4*)(xs + (size_t)s1 * 256 + c4);
        const ushort4 x2 = *(const ushort4*)(xs + (size_t)s2 * 256 + c4);
        const ushort4 x3 = *(const ushort4*)(xs + (size_t)s3 * 256 + c4);
        a0 = (a0 >= 0.f) ? a0 : LRELU_SLOPE * a0;
        a1 = (a1 >= 0.f) ? a1 : LRELU_SLOPE * a1;
        a2 = (a2 >= 0.f) ? a2 : LRELU_SLOPE * a2;
        a3 = (a3 >= 0.f) ? a3 : LRELU_SLOPE * a3;
        const float w0 = __expf(a0), w1 = __expf(a1);
        const float w2 = __expf(a2), w3 = __expf(a3);
        facc.x += w0 * bf2f(x0.x) + w1 * bf2f(x1.x) + w2 * bf2f(x2.x) + w3 * bf2f(x3.x);
        facc.y += w0 * bf2f(x0.y) + w1 * bf2f(x1.y) + w2 * bf2f(x2.y) + w3 * bf2f(x3.y);
        facc.z += w0 * bf2f(x0.z) + w1 * bf2f(x1.z) + w2 * bf2f(x2.z) + w3 * bf2f(x3.z);
        facc.w += w0 * bf2f(x0.w) + w1 * bf2f(x1.w) + w2 * bf2f(x2.w) + w3 * bf2f(x3.w);
        dacc   += w0 + w1 + w2 + w3;
    }
    for (; i < end; ++i) {
        const int s = ecsr[i];
        float a = aS[(size_t)s * 4 + h] + aDn;
        a = (a >= 0.f) ? a : LRELU_SLOPE * a;
        const float w = __expf(a);
        const ushort4 x = *(const ushort4*)(xs + (size_t)s * 256 + c4);
        facc.x += w * bf2f(x.x); facc.y += w * bf2f(x.y);
        facc.z += w * bf2f(x.z); facc.w += w * bf2f(x.w);
        dacc   += w;
    }

    const float inv = 1.f / fmaxf(dacc, 1e-16f);
    const float4 bv = *(const float4*)(bias + c4);
    float4 v;
    v.x = scale * (facc.x * inv + bv.x);
    v.y = scale * (facc.y * inv + bv.y);
    v.z = scale * (facc.z * inv + bv.z);
    v.w = scale * (facc.w * inv + bv.w);
    float4* ap = (float4*)(acc + (size_t)n * 256 + c4);
    if (init) {
        *ap = v;
    } else {
        float4 o = *ap;
        o.x += v.x; o.y += v.y; o.z += v.z; o.w += v.w;
        *ap = o;
    }
}

// ---- skip + relu + cast: htb = bf16(relu(acc + htb)) in place --------------
__global__ __launch_bounds__(256) void combine_relu(
    const float* __restrict__ acc, ushort* __restrict__ htb, int total4)
{
    const int idx = blockIdx.x * blockDim.x + threadIdx.x;
    if (idx >= total4) return;
    float4 a = ((const float4*)acc)[idx];
    ushort4 hb = ((const ushort4*)htb)[idx];
    ushort4 o;
    o.x = f2bf(fmaxf(a.x + bf2f(hb.x), 0.f));
    o.y = f2bf(fmaxf(a.y + bf2f(hb.y), 0.f));
    o.z = f2bf(fmaxf(a.z + bf2f(hb.z), 0.f));
    o.w = f2bf(fmaxf(a.w + bf2f(hb.w), 0.f));
    ((ushort4*)htb)[idx] = o;
}

// ---------------------------------------------------------------------------
extern "C" void kernel_launch(void* const* d_in, const int* in_sizes, int n_in,
                              void* d_out, int out_size, void* d_ws, size_t ws_size,
                              hipStream_t stream)
{
    const int NT   = in_sizes[0] / 128;
    const int NC   = in_sizes[1] / 64;
    const int E_TT = in_sizes[2] / 2;
    const int E_CT = in_sizes[3];

    const float* x_target = (const float*)d_in[0];
    const float* x_context= (const float*)d_in[1];
    const int*   ei_tt    = (const int*)d_in[2];
    const int*   ei_ct_src= (const int*)d_in[3];
    const int*   ei_ct_dst= (const int*)d_in[4];
    const float* Wt   = (const float*)d_in[5];
    const float* bt   = (const float*)d_in[6];
    const float* Wc   = (const float*)d_in[7];
    const float* bc   = (const float*)d_in[8];
    const float* W_s2d  = (const float*)d_in[9];
    const float* as_s2d = (const float*)d_in[10];
    const float* ad_s2d = (const float*)d_in[11];
    const float* b_s2d  = (const float*)d_in[12];
    const float* W_d2s  = (const float*)d_in[13];
    const float* as_d2s = (const float*)d_in[14];
    const float* ad_d2s = (const float*)d_in[15];
    const float* b_d2s  = (const float*)d_in[16];
    const float* W_ct_src = (const float*)d_in[17];
    const float* W_ct_dst = (const float*)d_in[18];
    const float* as_ct  = (const float*)d_in[19];
    const float* ad_ct  = (const float*)d_in[20];
    const float* b_ct   = (const float*)d_in[21];
    const float* W_out  = (const float*)d_in[22];
    const float* b_out  = (const float*)d_in[23];
    float* out = (float*)d_out;

    const int* tt_src = ei_tt;
    const int* tt_dst = ei_tt + E_TT;

    // ---- workspace carve-up ----
    float* ws = (float*)d_ws;
    size_t o = 0;
    float* acc = ws + o;               o += (size_t)NT * 256;
    ushort* htb = (ushort*)(ws + o);   o += (size_t)NT * 128;   // NT*256 bf16
    ushort* Pb  = (ushort*)(ws + o);   o += (size_t)NT * 128;
    ushort* hcb = (ushort*)(ws + o);   o += (size_t)NC * 128;
    ushort* PSb = (ushort*)(ws + o);   o += (size_t)NC * 128;
    ushort* xtb = (ushort*)(ws + o);   o += (size_t)NT * 64;    // NT*128 bf16
    ushort* xcb = (ushort*)(ws + o);   o += (size_t)NC * 32;
    int* eA = (int*)(ws + o);          o += (size_t)E_TT;
    int* eB = (int*)(ws + o);          o += (size_t)E_TT;
    int* eC = (int*)(ws + o);          o += (size_t)E_CT;
    int* cnt = (int*)(ws + o);         o += (size_t)NT * 3;     // A,B,C
    int* ptr = (int*)(ws + o);         o += (size_t)(NT + 1) * 3;
    int* cur = (int*)(ws + o);         o += (size_t)NT * 3;
    int* bsum = (int*)(ws + o);        o += 256;                // 3*nblk <= 192
    float* aS  = ws + o;               o += (size_t)NT * 4;
    float* aD  = ws + o;               o += (size_t)NT * 4;
    float* wfold = ws + o;             o += 1024;
    ushort* WtT   = (ushort*)(ws + o); o += 128 * 256 / 2;
    ushort* WcT   = (ushort*)(ws + o); o += 64 * 256 / 2;
    ushort* W4T   = (ushort*)(ws + o); o += 4 * 256 * 256 / 2;  // s2d,d2s,ct_src,out
    (void)ws_size; (void)n_in; (void)out_size;

    ushort* Ws2dT = W4T;
    ushort* Wd2sT = W4T + 65536;
    ushort* WctsT = W4T + 2 * 65536;
    ushort* WoutT = W4T + 3 * 65536;

    int* cntA = cnt;           int* cntB = cnt + NT;           int* cntC = cnt + 2 * NT;
    int* ptrA = ptr;           int* ptrB = ptr + (NT + 1);     int* ptrC = ptr + 2 * (NT + 1);
    int* curA = cur;           int* curB = cur + NT;           int* curC = cur + 2 * NT;

    const dim3 blk(256);
    const int gN4 = (NT * 4 + 255) / 256;
    const int gGat = (NT + 3) / 4;
    const int nblk = (NT + 1023) / 1024;    // <= 64 for NT <= 65536

    auto gemm = [&](const ushort* A, const ushort* Bt, const float* bias,
                    float* Cf, ushort* Cb, int M, int K, int relu,
                    const float* attS, const float* attD, float* aSo, float* aDo) {
        dim3 grid((M + 63) / 64);
        hipLaunchKernelGGL(gemm_bf16, grid, blk, 0, stream, A, Bt, bias, Cf, Cb,
                           M, K, relu, attS, attD, aSo, aDo);
    };

    // 0) casts, weight transposes, CSR topology (feature-independent)
    hipMemsetAsync(cnt, 0, (size_t)NT * 3 * sizeof(int), stream);
    hipLaunchKernelGGL(cast_bf16, dim3((NT * 128 / 4 + 255) / 256), blk, 0, stream,
                       x_target, xtb, NT * 128 / 4);
    hipLaunchKernelGGL(cast_bf16, dim3((NC * 64 / 4 + 255) / 256), blk, 0, stream,
                       x_context, xcb, NC * 64 / 4);
    hipLaunchKernelGGL(wtrans, dim3(128), blk, 0, stream, Wt, WtT, 128);
    hipLaunchKernelGGL(wtrans, dim3(64),  blk, 0, stream, Wc, WcT, 64);
    hipLaunchKernelGGL(wtrans4, dim3(1024), blk, 0, stream,
                       W_s2d, W_d2s, W_ct_src, W_out, W4T);
    hipLaunchKernelGGL(csr_count_tt, dim3((E_TT + 255) / 256), blk, 0, stream,
                       tt_src, tt_dst, E_TT, cntA, cntB);
    hipLaunchKernelGGL(csr_count, dim3((E_CT + 255) / 256), blk, 0, stream,
                       ei_ct_dst, E_CT, cntC);
    hipLaunchKernelGGL(scan_part, dim3(nblk, 3), blk, 0, stream, cnt, bsum, NT, nblk);
    hipLaunchKernelGGL(scan_base, dim3(1), blk, 0, stream, bsum, ptr, NT, nblk);
    hipLaunchKernelGGL(scan_final, dim3(nblk, 3), blk, 0, stream, cnt, bsum, ptr, cur, NT, nblk);
    hipLaunchKernelGGL(csr_place_tt, dim3((E_TT + 255) / 256), blk, 0, stream,
                       tt_src, tt_dst, E_TT, curA, eA, curB, eB);
    hipLaunchKernelGGL(csr_place, dim3((E_CT + 255) / 256), blk, 0, stream,
                       ei_ct_src, ei_ct_dst, E_CT, curC, eC);

    // 1) pretransform
    gemm(xtb, WtT, bt, nullptr, htb, NT, 128, 1, nullptr, nullptr, nullptr, nullptr);
    gemm(xcb, WcT, bc, nullptr, hcb, NC, 64, 1, nullptr, nullptr, nullptr, nullptr);

    // ---- GAT s2d ----
    gemm(htb, Ws2dT, nullptr, nullptr, Pb, NT, 256, 0, as_s2d, ad_s2d, aS, aD);
    hipLaunchKernelGGL(gat_gather_csr, dim3(gGat), blk, 0, stream,
                       ptrA, eA, aS, aD, Pb, b_s2d, 0.25f, acc, NT, 1, 1);

    // ---- GAT d2s (reversed roles) ----
    gemm(htb, Wd2sT, nullptr, nullptr, Pb, NT, 256, 0, as_d2s, ad_d2s, aS, aD);
    hipLaunchKernelGGL(gat_gather_csr, dim3(gGat), blk, 0, stream,
                       ptrB, eB, aS, aD, Pb, b_d2s, 0.25f, acc, NT, 1, 0);

    // ---- GAT ct (no self loops; aD via folded projection) ----
    gemm(hcb, WctsT, nullptr, nullptr, PSb, NC, 256, 0, as_ct, nullptr, aS, nullptr);
    hipLaunchKernelGGL(fold_ct, dim3(4), blk, 0, stream, W_ct_dst, ad_ct, wfold);
    hipLaunchKernelGGL(alpha_from_fold, dim3(gN4), blk, 0, stream, htb, wfold, aD, NT);
    hipLaunchKernelGGL(gat_gather_csr, dim3(gGat), blk, 0, stream,
                       ptrC, eC, aS, aD, PSb, b_ct, 0.5f, acc, NT, 0, 0);

    // ---- skip + relu (bf16 in place), final linear ----
    hipLaunchKernelGGL(combine_relu, dim3((NT * 64 + 255) / 256), blk, 0, stream,
                       acc, htb, NT * 64);
    gemm(htb, WoutT, b_out, out, nullptr, NT, 256, 0, nullptr, nullptr, nullptr, nullptr);
}